// Round 2
// 122.322 us; speedup vs baseline: 1.1634x; 1.1634x over previous
//
#include <hip/hip_runtime.h>
#include <hip/hip_bf16.h>

#define NB  8
#define ENW 512
#define DEW 64
#define EMB 512
#define UN  512
#define NT  100

// k = 2*log2(e): folded into w_en, w_de, tw so that exp2(att2+bias2) = e^{2x}
#define KSCALE 2.8853900817779268f
#define L2E    1.4426950408889634f

typedef short bf16x8 __attribute__((ext_vector_type(8)));
typedef unsigned short u16x8 __attribute__((ext_vector_type(8)));
typedef float f32x4  __attribute__((ext_vector_type(4)));

#define GLOAD_LDS16(src, dst) __builtin_amdgcn_global_load_lds( \
    (const __attribute__((address_space(1))) void*)(src),       \
    (__attribute__((address_space(3))) void*)(dst), 16, 0, 0)

__device__ __forceinline__ unsigned short f2bf(float f) {   // RNE
    union { float f; unsigned int u; } v; v.f = f;
    unsigned int r = v.u + 0x7FFFu + ((v.u >> 16) & 1u);
    return (unsigned short)(r >> 16);
}

// ---------------- fused prep ----------------
// bx 0..63:      wen_t[u][e] = bf16(K*w_en[e][u])   (LDS tile transpose)
// bx 64..127:    wde_t[u][e] = bf16(K*w_de[e][u])
// bx 128..1151:  en_bf = bf16(en)
// bx 1152..1279: de_bf = bf16(de)
// bx 1280..1295: tw2[b][u] = K * sum_t topics[b][t]*wt[u][t]
// bx 1296:       snu[0] = sum_u nu[u];  nu2[u] = -2*nu[u]
__global__ __launch_bounds__(256) void prep_kernel(const float* __restrict__ w_en,
                                                   const float* __restrict__ w_de,
                                                   const float* __restrict__ en,
                                                   const float* __restrict__ de,
                                                   const float* __restrict__ topics,
                                                   const float* __restrict__ wt_mat,
                                                   const float* __restrict__ nu,
                                                   unsigned short* __restrict__ wen_t,
                                                   unsigned short* __restrict__ wde_t,
                                                   unsigned short* __restrict__ en_bf,
                                                   unsigned short* __restrict__ de_bf,
                                                   float* __restrict__ tw2,
                                                   float* __restrict__ snu,
                                                   float* __restrict__ nu2) {
    const int bx = blockIdx.x, t = threadIdx.x;
    if (bx < 128) {
        __shared__ float tile[64][65];
        const float* w = (bx < 64) ? w_en : w_de;
        unsigned short* o = (bx < 64) ? wen_t : wde_t;
        const int tb = bx & 63;
        const int r0 = (tb >> 3) * 64;      // e-range
        const int c0 = (tb & 7) * 64;       // u-range
        const int rr = t >> 4, cc = (t & 15) * 4;
#pragma unroll
        for (int q = 0; q < 4; ++q) {
            float4 v = *(const float4*)(w + (size_t)(r0 + rr + 16 * q) * 512 + c0 + cc);
            *(float4*)&tile[rr + 16 * q][cc] = v;
        }
        __syncthreads();
#pragma unroll
        for (int q = 0; q < 4; ++q) {
            int ul = rr + 16 * q;
            int el = cc;
            ushort4 v;
            v.x = f2bf(KSCALE * tile[el][ul]);
            v.y = f2bf(KSCALE * tile[el + 1][ul]);
            v.z = f2bf(KSCALE * tile[el + 2][ul]);
            v.w = f2bf(KSCALE * tile[el + 3][ul]);
            *(ushort4*)(o + (size_t)(c0 + ul) * 512 + r0 + el) = v;
        }
    } else if (bx < 1280) {
        const bool is_en = (bx < 1152);
        const float* src = is_en ? en : de;
        unsigned short* dst = is_en ? en_bf : de_bf;
        const int idx = ((is_en ? (bx - 128) : (bx - 1152)) * 256 + t) * 8;
        float4 a0 = *(const float4*)(src + idx);
        float4 a1 = *(const float4*)(src + idx + 4);
        u16x8 o;
        o[0] = f2bf(a0.x); o[1] = f2bf(a0.y); o[2] = f2bf(a0.z); o[3] = f2bf(a0.w);
        o[4] = f2bf(a1.x); o[5] = f2bf(a1.y); o[6] = f2bf(a1.z); o[7] = f2bf(a1.w);
        *(u16x8*)(dst + idx) = o;
    } else if (bx < 1296) {
        int idx = (bx - 1280) * 256 + t;      // b*512+u
        int b = idx >> 9, u = idx & 511;
        const float* tp = topics + b * NT;
        const float* wp = wt_mat + u * NT;
        float s = 0.f;
        for (int tt = 0; tt < NT; ++tt) s += tp[tt] * wp[tt];
        tw2[idx] = KSCALE * s;
    } else {
        __shared__ float red[256];
        float n0 = nu[t], n1 = nu[t + 256];
        nu2[t] = -2.f * n0;
        nu2[t + 256] = -2.f * n1;
        red[t] = n0 + n1;
        __syncthreads();
        for (int off = 128; off > 0; off >>= 1) {
            if (t < off) red[t] += red[t + off];
            __syncthreads();
        }
        if (t == 0) snu[0] = red[0];
    }
}

// ---------------- fused MFMA GEMM (en + de), bf16 A, exp2 epilogue ----------------
// Whole 64x512 B-tile staged ONCE into LDS via global_load_lds (source XOR-swizzled,
// linear dest; reads apply the same swizzle -> conflict-free ds_read_b128).
// K-loop: zero global B traffic, zero barriers; A streams direct from L2.
__global__ __launch_bounds__(256) void gemm_fused(const unsigned short* __restrict__ en_bf,
                                                  const unsigned short* __restrict__ de_bf,
                                                  const unsigned short* __restrict__ wen_t,
                                                  const unsigned short* __restrict__ wde_t,
                                                  const float* __restrict__ tw2,
                                                  float* __restrict__ Ea,
                                                  float* __restrict__ Eb) {
    __shared__ unsigned short Blds[64 * 512];   // 64 KB
    const int K = 512, N = 512;
    const int bx = blockIdx.x;
    const bool is_de = (bx >= 64);
    const unsigned short* A = is_de ? de_bf : en_bf;
    const unsigned short* Bt = is_de ? wde_t : wen_t;
    float* C = is_de ? Eb : Ea;
    const int mb = is_de ? (bx - 64) : bx;

    const int lane = threadIdx.x & 63;
    const int wave = threadIdx.x >> 6;
    const int n0 = blockIdx.y * 64;

    // stage B-tile: wave w stages rows w*16..w*16+15 (1 KB per instr, linear LDS dest;
    // swizzle applied on the per-lane GLOBAL source address)
#pragma unroll
    for (int q = 0; q < 16; ++q) {
        const int R = wave * 16 + q;
        const unsigned short* src = Bt + (size_t)(n0 + R) * K + ((lane * 8) ^ ((R & 7) << 3));
        GLOAD_LDS16(src, &Blds[R * 512]);
    }

    const int m0 = mb * 64 + wave * 16;
    const int row = m0 + (lane & 15);
    const int kq  = (lane >> 4) * 8;
    const int nrow = lane & 15;
    const int swz = (nrow & 7) << 3;           // same for all nn since 16 ≡ 0 (mod 8)

    f32x4 acc[4];
#pragma unroll
    for (int nn = 0; nn < 4; ++nn) acc[nn] = 0.f;

    const unsigned short* ap = A + (size_t)row * K + kq;
    __syncthreads();                            // drains vmcnt(0): staging complete
#pragma unroll 4
    for (int kc = 0; kc < K; kc += 32) {
        bf16x8 a = *(const bf16x8*)(ap + kc);
        const int col = (kq + kc) ^ swz;
#pragma unroll
        for (int nn = 0; nn < 4; ++nn) {
            bf16x8 b = *(const bf16x8*)&Blds[(nrow + nn * 16) * 512 + col];
            acc[nn] = __builtin_amdgcn_mfma_f32_16x16x32_bf16(a, b, acc[nn], 0, 0, 0);
        }
    }
    const int crow = m0 + (lane >> 4) * 4;
    const int ccol = lane & 15;
#pragma unroll
    for (int nn = 0; nn < 4; ++nn)
#pragma unroll
        for (int r = 0; r < 4; ++r) {
            int rw = crow + r, cl = n0 + nn * 16 + ccol;
            float v = acc[nn][r];
            if (is_de) v += tw2[(rw >> 6) * 512 + cl];
            C[(size_t)rw * N + cl] = __builtin_amdgcn_exp2f(v);
        }
}

// ---------------- mu partials: register-tiled 1j x 4i per thread ----------------
// mu_part[b][j][i] = sum_{u in half} nu2_u * rcp(Ea[b][i][u]*Eb[b][j][u] + 1)
// grid 512 = b(8) x jt(4) x it(8) x us(2); block tile 16j x 64i, 256 u's per block.
// Per 4-u chunk: 16 rcp vs 5 LDS b128 (nu2 via uniform scalar load) -> VALU-bound.
__global__ __launch_bounds__(256) void mu5_kernel(const float* __restrict__ Ea,
                                                  const float* __restrict__ Eb,
                                                  const float* __restrict__ nu2,
                                                  float* __restrict__ mu0,
                                                  float* __restrict__ mu1) {
    __shared__ float As[64][132];
    __shared__ float Bs[16][132];
    const int t = threadIdx.x;
    const int bx = blockIdx.x;
    const int us = bx & 1;
    const int it = (bx >> 1) & 7;
    const int jt = (bx >> 4) & 3;
    const int b  = bx >> 6;
    const int i0 = it * 64, j0 = jt * 16, u0 = us * 256;
    const int il = t & 15, jr = t >> 4;

    const float* aeb = Ea + (size_t)(b * ENW + i0) * UN;
    const float* beb = Eb + (size_t)(b * DEW + j0) * UN;

    float s0 = 0.f, s1 = 0.f, s2 = 0.f, s3 = 0.f;
#pragma unroll
    for (int half = 0; half < 2; ++half) {
        const int uc = u0 + half * 128;
#pragma unroll
        for (int q = 0; q < 8; ++q) {
            int idx = q * 256 + t;
            int rowi = idx >> 5, c4 = idx & 31;
            *(float4*)&As[rowi][c4 * 4] = *(const float4*)(aeb + (size_t)rowi * UN + uc + c4 * 4);
        }
#pragma unroll
        for (int q = 0; q < 2; ++q) {
            int idx = q * 256 + t;
            int rowi = idx >> 5, c4 = idx & 31;
            *(float4*)&Bs[rowi][c4 * 4] = *(const float4*)(beb + (size_t)rowi * UN + uc + c4 * 4);
        }
        __syncthreads();
#pragma unroll 8
        for (int c = 0; c < 32; ++c) {
            float4 bb = *(const float4*)&Bs[jr][c * 4];
            float4 nv = *(const float4*)(nu2 + uc + c * 4);   // uniform -> s_load
            float4 a0 = *(const float4*)&As[il][c * 4];
            float4 a1 = *(const float4*)&As[il + 16][c * 4];
            float4 a2 = *(const float4*)&As[il + 32][c * 4];
            float4 a3 = *(const float4*)&As[il + 48][c * 4];
            s0 = fmaf(nv.x, __builtin_amdgcn_rcpf(fmaf(a0.x, bb.x, 1.f)), s0);
            s0 = fmaf(nv.y, __builtin_amdgcn_rcpf(fmaf(a0.y, bb.y, 1.f)), s0);
            s0 = fmaf(nv.z, __builtin_amdgcn_rcpf(fmaf(a0.z, bb.z, 1.f)), s0);
            s0 = fmaf(nv.w, __builtin_amdgcn_rcpf(fmaf(a0.w, bb.w, 1.f)), s0);
            s1 = fmaf(nv.x, __builtin_amdgcn_rcpf(fmaf(a1.x, bb.x, 1.f)), s1);
            s1 = fmaf(nv.y, __builtin_amdgcn_rcpf(fmaf(a1.y, bb.y, 1.f)), s1);
            s1 = fmaf(nv.z, __builtin_amdgcn_rcpf(fmaf(a1.z, bb.z, 1.f)), s1);
            s1 = fmaf(nv.w, __builtin_amdgcn_rcpf(fmaf(a1.w, bb.w, 1.f)), s1);
            s2 = fmaf(nv.x, __builtin_amdgcn_rcpf(fmaf(a2.x, bb.x, 1.f)), s2);
            s2 = fmaf(nv.y, __builtin_amdgcn_rcpf(fmaf(a2.y, bb.y, 1.f)), s2);
            s2 = fmaf(nv.z, __builtin_amdgcn_rcpf(fmaf(a2.z, bb.z, 1.f)), s2);
            s2 = fmaf(nv.w, __builtin_amdgcn_rcpf(fmaf(a2.w, bb.w, 1.f)), s2);
            s3 = fmaf(nv.x, __builtin_amdgcn_rcpf(fmaf(a3.x, bb.x, 1.f)), s3);
            s3 = fmaf(nv.y, __builtin_amdgcn_rcpf(fmaf(a3.y, bb.y, 1.f)), s3);
            s3 = fmaf(nv.z, __builtin_amdgcn_rcpf(fmaf(a3.z, bb.z, 1.f)), s3);
            s3 = fmaf(nv.w, __builtin_amdgcn_rcpf(fmaf(a3.w, bb.w, 1.f)), s3);
        }
        __syncthreads();
    }
    float* mo = us ? mu1 : mu0;
    const size_t base = (size_t)(b * DEW + j0 + jr) * ENW + i0 + il;
    mo[base]      = s0;
    mo[base + 16] = s1;
    mo[base + 32] = s2;
    mo[base + 48] = s3;
}

// ---------------- fused softmax + p_gen + alphas + out ----------------
// grid 256: eh=bx&1, jq=(bx>>1)&15, b=bx>>5. 4 waves: phase1 wave=j (softmax);
// phase2 wave=i-quarter, lane=4e of this e-half; phase3 LDS cross-wave reduce.
// mu = mu0 + mu1 + snu (u-split partials recombined here).
__global__ __launch_bounds__(256) void softfin_kernel(const float* __restrict__ mu0,
                                                      const float* __restrict__ mu1,
                                                      const float* __restrict__ snu,
                                                      const float* __restrict__ en,
                                                      const float* __restrict__ de,
                                                      float* __restrict__ out,
                                                      float* __restrict__ alphas,
                                                      float* __restrict__ p_gen) {
    __shared__ float Al[4][512];
    __shared__ float Ps[4][4][256];
    const int bx = blockIdx.x;
    const int eh = bx & 1;
    const int jq = (bx >> 1) & 15;
    const int b  = bx >> 5;
    const int t = threadIdx.x;
    const int wave = t >> 6, lane = t & 63;
    const int j0 = jq * 4;
    const float snu0 = snu[0];

    // ---- phase 1: softmax for j = j0 + wave ----
    {
        const int bj = b * DEW + j0 + wave;
        const float* mup0 = mu0 + (size_t)bj * ENW;
        const float* mup1 = mu1 + (size_t)bj * ENW;
        float v[8], a[8];
#pragma unroll
        for (int c = 0; c < 8; ++c) v[c] = mup0[c * 64 + lane] + mup1[c * 64 + lane] + snu0;
        float mx = v[0];
#pragma unroll
        for (int c = 1; c < 8; ++c) mx = fmaxf(mx, v[c]);
#pragma unroll
        for (int off = 32; off > 0; off >>= 1) mx = fmaxf(mx, __shfl_xor(mx, off));
        float s = 0.f;
#pragma unroll
        for (int c = 0; c < 8; ++c) { a[c] = __builtin_amdgcn_exp2f((v[c] - mx) * L2E); s += a[c]; }
#pragma unroll
        for (int off = 32; off > 0; off >>= 1) s += __shfl_xor(s, off);
        float inv = __builtin_amdgcn_rcpf(s);
#pragma unroll
        for (int c = 0; c < 8; ++c) {
            a[c] *= inv;
            Al[wave][c * 64 + lane] = a[c];
        }
        if (eh == 0) {
            float* alp = alphas + (size_t)bj * ENW;
            float* pgp = p_gen + (size_t)bj * ENW;
#pragma unroll
            for (int c = 0; c < 8; ++c) {
                alp[c * 64 + lane] = a[c];
                pgp[c * 64 + lane] = __builtin_amdgcn_rcpf(1.f + __builtin_amdgcn_exp2f(-v[c] * L2E));
            }
        }
    }
    __syncthreads();

    // ---- phase 2: partial sums over i-quarter `wave` ----
    const int i0 = wave * 128;
    const float* enb = en + (size_t)b * ENW * EMB + eh * 256 + lane * 4;
    f32x4 acc[4];
#pragma unroll
    for (int jj = 0; jj < 4; ++jj) acc[jj] = 0.f;
#pragma unroll 2
    for (int ig = 0; ig < 128; ig += 4) {
        const int ib = i0 + ig;
        float4 al0 = *(const float4*)&Al[0][ib];
        float4 al1 = *(const float4*)&Al[1][ib];
        float4 al2 = *(const float4*)&Al[2][ib];
        float4 al3 = *(const float4*)&Al[3][ib];
#pragma unroll
        for (int r = 0; r < 4; ++r) {
            float4 x = *(const float4*)(enb + (size_t)(ib + r) * EMB);
            float w0 = (r == 0) ? al0.x : (r == 1) ? al0.y : (r == 2) ? al0.z : al0.w;
            float w1 = (r == 0) ? al1.x : (r == 1) ? al1.y : (r == 2) ? al1.z : al1.w;
            float w2 = (r == 0) ? al2.x : (r == 1) ? al2.y : (r == 2) ? al2.z : al2.w;
            float w3 = (r == 0) ? al3.x : (r == 1) ? al3.y : (r == 2) ? al3.z : al3.w;
            acc[0][0] = fmaf(w0, x.x, acc[0][0]); acc[0][1] = fmaf(w0, x.y, acc[0][1]);
            acc[0][2] = fmaf(w0, x.z, acc[0][2]); acc[0][3] = fmaf(w0, x.w, acc[0][3]);
            acc[1][0] = fmaf(w1, x.x, acc[1][0]); acc[1][1] = fmaf(w1, x.y, acc[1][1]);
            acc[1][2] = fmaf(w1, x.z, acc[1][2]); acc[1][3] = fmaf(w1, x.w, acc[1][3]);
            acc[2][0] = fmaf(w2, x.x, acc[2][0]); acc[2][1] = fmaf(w2, x.y, acc[2][1]);
            acc[2][2] = fmaf(w2, x.z, acc[2][2]); acc[2][3] = fmaf(w2, x.w, acc[2][3]);
            acc[3][0] = fmaf(w3, x.x, acc[3][0]); acc[3][1] = fmaf(w3, x.y, acc[3][1]);
            acc[3][2] = fmaf(w3, x.z, acc[3][2]); acc[3][3] = fmaf(w3, x.w, acc[3][3]);
        }
    }
#pragma unroll
    for (int jj = 0; jj < 4; ++jj)
        *(f32x4*)&Ps[wave][jj][lane * 4] = acc[jj];
    __syncthreads();

    // ---- phase 3: reduce over i-quarters; wave handles its own j ----
    {
        const int bj = b * DEW + j0 + wave;
        const int e = eh * 256 + lane * 4;
        float4 p0 = *(const float4*)&Ps[0][wave][lane * 4];
        float4 p1 = *(const float4*)&Ps[1][wave][lane * 4];
        float4 p2 = *(const float4*)&Ps[2][wave][lane * 4];
        float4 p3 = *(const float4*)&Ps[3][wave][lane * 4];
        float4 d = *(const float4*)(de + (size_t)bj * EMB + e);
        float4 o;
        o.x = d.x + (p0.x + p1.x) + (p2.x + p3.x);
        o.y = d.y + (p0.y + p1.y) + (p2.y + p3.y);
        o.z = d.z + (p0.z + p1.z) + (p2.z + p3.z);
        o.w = d.w + (p0.w + p1.w) + (p2.w + p3.w);
        *(float4*)(out + (size_t)bj * EMB + e) = o;
    }
}

extern "C" void kernel_launch(void* const* d_in, const int* in_sizes, int n_in,
                              void* d_out, int out_size, void* d_ws, size_t ws_size,
                              hipStream_t stream) {
    const float* en     = (const float*)d_in[0];  // [8][512][512]
    const float* de     = (const float*)d_in[1];  // [8][64][512]
    const float* topics = (const float*)d_in[2];  // [8][100]
    const float* w_en   = (const float*)d_in[3];  // [512][512]
    const float* w_de   = (const float*)d_in[4];  // [512][512]
    const float* nu     = (const float*)d_in[5];  // [512]
    const float* wt     = (const float*)d_in[6];  // [512][100]

    float* out    = (float*)d_out;        // [8][64][512]
    float* alphas = out + 262144;
    float* p_gen  = out + 524288;

    // Workspace layout (total 15,222,800 B — below round-0's proven 16,271,376 B).
    // mu0/mu1 ALIAS the en_bf region: en_bf is dead after gemm_fused, mu0/mu1 are
    // first written by mu5_kernel (strictly later on the same stream).
    char* ws = (char*)d_ws;
    float* Ea             = (float*)(ws);                       //  8388608 B
    float* Eb             = (float*)(ws + 8388608);             //  1048576 B
    float* tw2            = (float*)(ws + 9437184);             //    16384 B
    unsigned short* en_bf = (unsigned short*)(ws + 9453568);    //  4194304 B
    float* mu0            = (float*)(ws + 9453568);             //  1048576 B (alias en_bf)
    float* mu1            = (float*)(ws + 10502144);            //  1048576 B (alias en_bf)
    unsigned short* de_bf = (unsigned short*)(ws + 13647872);   //   524288 B
    unsigned short* wen_t = (unsigned short*)(ws + 14172160);   //   524288 B
    unsigned short* wde_t = (unsigned short*)(ws + 14696448);   //   524288 B
    float* snu            = (float*)(ws + 15220736);            //       16 B
    float* nu2            = (float*)(ws + 15220752);            //     2048 B

    prep_kernel<<<1297, 256, 0, stream>>>(w_en, w_de, en, de, topics, wt, nu,
                                          wen_t, wde_t, en_bf, de_bf, tw2, snu, nu2);
    gemm_fused<<<dim3(72, 8), 256, 0, stream>>>(en_bf, de_bf, wen_t, wde_t, tw2, Ea, Eb);
    mu5_kernel<<<512, 256, 0, stream>>>(Ea, Eb, nu2, mu0, mu1);
    softfin_kernel<<<256, 256, 0, stream>>>(mu0, mu1, snu, en, de, out, alphas, p_gen);
}

// Round 3
// 121.055 us; speedup vs baseline: 1.1756x; 1.0105x over previous
//
#include <hip/hip_runtime.h>
#include <hip/hip_bf16.h>

#define NB  8
#define ENW 512
#define DEW 64
#define EMB 512
#define UN  512
#define NT  100

// k = 2*log2(e): folded into w_en, w_de, tw so that exp2(att2+bias2) = e^{2x}
#define KSCALE 2.8853900817779268f
#define L2E    1.4426950408889634f

typedef short bf16x8 __attribute__((ext_vector_type(8)));
typedef unsigned short u16x8 __attribute__((ext_vector_type(8)));
typedef float f32x4  __attribute__((ext_vector_type(4)));

#define GLOAD_LDS16(src, dst) __builtin_amdgcn_global_load_lds( \
    (const __attribute__((address_space(1))) void*)(src),       \
    (__attribute__((address_space(3))) void*)(dst), 16, 0, 0)

__device__ __forceinline__ unsigned short f2bf(float f) {   // RNE
    union { float f; unsigned int u; } v; v.f = f;
    unsigned int r = v.u + 0x7FFFu + ((v.u >> 16) & 1u);
    return (unsigned short)(r >> 16);
}

// ---------------- fused prep ----------------
// bx 0..63:      wen_t[u][e] = bf16(K*w_en[e][u])   (LDS tile transpose)
// bx 64..127:    wde_t[u][e] = bf16(K*w_de[e][u])
// bx 128..1151:  en_bf = bf16(en)
// bx 1152..1279: de_bf = bf16(de)
// bx 1280..1295: tw2[b][u] = K * sum_t topics[b][t]*wt[u][t]
// bx 1296:       snu[0] = sum_u nu[u];  nu2[u] = -2*nu[u]
__global__ __launch_bounds__(256) void prep_kernel(const float* __restrict__ w_en,
                                                   const float* __restrict__ w_de,
                                                   const float* __restrict__ en,
                                                   const float* __restrict__ de,
                                                   const float* __restrict__ topics,
                                                   const float* __restrict__ wt_mat,
                                                   const float* __restrict__ nu,
                                                   unsigned short* __restrict__ wen_t,
                                                   unsigned short* __restrict__ wde_t,
                                                   unsigned short* __restrict__ en_bf,
                                                   unsigned short* __restrict__ de_bf,
                                                   float* __restrict__ tw2,
                                                   float* __restrict__ snu,
                                                   float* __restrict__ nu2) {
    const int bx = blockIdx.x, t = threadIdx.x;
    if (bx < 128) {
        __shared__ float tile[64][65];
        const float* w = (bx < 64) ? w_en : w_de;
        unsigned short* o = (bx < 64) ? wen_t : wde_t;
        const int tb = bx & 63;
        const int r0 = (tb >> 3) * 64;      // e-range
        const int c0 = (tb & 7) * 64;       // u-range
        const int rr = t >> 4, cc = (t & 15) * 4;
#pragma unroll
        for (int q = 0; q < 4; ++q) {
            float4 v = *(const float4*)(w + (size_t)(r0 + rr + 16 * q) * 512 + c0 + cc);
            *(float4*)&tile[rr + 16 * q][cc] = v;
        }
        __syncthreads();
#pragma unroll
        for (int q = 0; q < 4; ++q) {
            int ul = rr + 16 * q;
            int el = cc;
            ushort4 v;
            v.x = f2bf(KSCALE * tile[el][ul]);
            v.y = f2bf(KSCALE * tile[el + 1][ul]);
            v.z = f2bf(KSCALE * tile[el + 2][ul]);
            v.w = f2bf(KSCALE * tile[el + 3][ul]);
            *(ushort4*)(o + (size_t)(c0 + ul) * 512 + r0 + el) = v;
        }
    } else if (bx < 1280) {
        const bool is_en = (bx < 1152);
        const float* src = is_en ? en : de;
        unsigned short* dst = is_en ? en_bf : de_bf;
        const int idx = ((is_en ? (bx - 128) : (bx - 1152)) * 256 + t) * 8;
        float4 a0 = *(const float4*)(src + idx);
        float4 a1 = *(const float4*)(src + idx + 4);
        u16x8 o;
        o[0] = f2bf(a0.x); o[1] = f2bf(a0.y); o[2] = f2bf(a0.z); o[3] = f2bf(a0.w);
        o[4] = f2bf(a1.x); o[5] = f2bf(a1.y); o[6] = f2bf(a1.z); o[7] = f2bf(a1.w);
        *(u16x8*)(dst + idx) = o;
    } else if (bx < 1296) {
        int idx = (bx - 1280) * 256 + t;      // b*512+u
        int b = idx >> 9, u = idx & 511;
        const float* tp = topics + b * NT;
        const float* wp = wt_mat + u * NT;
        float s = 0.f;
        for (int tt = 0; tt < NT; ++tt) s += tp[tt] * wp[tt];
        tw2[idx] = KSCALE * s;
    } else {
        __shared__ float red[256];
        float n0 = nu[t], n1 = nu[t + 256];
        nu2[t] = -2.f * n0;
        nu2[t + 256] = -2.f * n1;
        red[t] = n0 + n1;
        __syncthreads();
        for (int off = 128; off > 0; off >>= 1) {
            if (t < off) red[t] += red[t + off];
            __syncthreads();
        }
        if (t == 0) snu[0] = red[0];
    }
}

// ---------------- fused MFMA GEMM (en + de), bf16 A, exp2 epilogue ----------------
// Whole 64x512 B-tile staged ONCE into LDS via global_load_lds (source XOR-swizzled,
// linear dest; reads apply the same swizzle -> conflict-free ds_read_b128).
// A-path software-pipelined: first 4 loads hoisted above the barrier, next group
// prefetched before each MFMA cluster.
__global__ __launch_bounds__(256) void gemm_fused(const unsigned short* __restrict__ en_bf,
                                                  const unsigned short* __restrict__ de_bf,
                                                  const unsigned short* __restrict__ wen_t,
                                                  const unsigned short* __restrict__ wde_t,
                                                  const float* __restrict__ tw2,
                                                  float* __restrict__ Ea,
                                                  float* __restrict__ Eb) {
    __shared__ unsigned short Blds[64 * 512];   // 64 KB
    const int K = 512, N = 512;
    const int bx = blockIdx.x;
    const bool is_de = (bx >= 64);
    const unsigned short* A = is_de ? de_bf : en_bf;
    const unsigned short* Bt = is_de ? wde_t : wen_t;
    float* C = is_de ? Eb : Ea;
    const int mb = is_de ? (bx - 64) : bx;

    const int lane = threadIdx.x & 63;
    const int wave = threadIdx.x >> 6;
    const int n0 = blockIdx.y * 64;

    // stage B-tile: wave w stages rows w*16..w*16+15 (1 KB per instr, linear LDS dest;
    // swizzle applied on the per-lane GLOBAL source address)
#pragma unroll
    for (int q = 0; q < 16; ++q) {
        const int R = wave * 16 + q;
        const unsigned short* src = Bt + (size_t)(n0 + R) * K + ((lane * 8) ^ ((R & 7) << 3));
        GLOAD_LDS16(src, &Blds[R * 512]);
    }

    const int m0 = mb * 64 + wave * 16;
    const int row = m0 + (lane & 15);
    const int kq  = (lane >> 4) * 8;
    const int nrow = lane & 15;
    const int swz = (nrow & 7) << 3;           // same for all nn since 16 ≡ 0 (mod 8)

    f32x4 acc[4];
#pragma unroll
    for (int nn = 0; nn < 4; ++nn) acc[nn] = 0.f;

    const unsigned short* ap = A + (size_t)row * K + kq;
    // prefetch first A group BEFORE the barrier (independent of LDS staging)
    bf16x8 apre[4];
#pragma unroll
    for (int q = 0; q < 4; ++q) apre[q] = *(const bf16x8*)(ap + q * 32);

    __syncthreads();                            // drains vmcnt(0): staging complete
#pragma unroll
    for (int g = 0; g < 4; ++g) {
        bf16x8 acur[4];
#pragma unroll
        for (int q = 0; q < 4; ++q) acur[q] = apre[q];
        if (g < 3) {
#pragma unroll
            for (int q = 0; q < 4; ++q) apre[q] = *(const bf16x8*)(ap + (g + 1) * 128 + q * 32);
        }
#pragma unroll
        for (int q = 0; q < 4; ++q) {
            const int kc = g * 128 + q * 32;
            const int col = (kq + kc) ^ swz;
#pragma unroll
            for (int nn = 0; nn < 4; ++nn) {
                bf16x8 b = *(const bf16x8*)&Blds[(nrow + nn * 16) * 512 + col];
                acc[nn] = __builtin_amdgcn_mfma_f32_16x16x32_bf16(acur[q], b, acc[nn], 0, 0, 0);
            }
        }
    }
    const int crow = m0 + (lane >> 4) * 4;
    const int ccol = lane & 15;
#pragma unroll
    for (int nn = 0; nn < 4; ++nn)
#pragma unroll
        for (int r = 0; r < 4; ++r) {
            int rw = crow + r, cl = n0 + nn * 16 + ccol;
            float v = acc[nn][r];
            if (is_de) v += tw2[(rw >> 6) * 512 + cl];
            C[(size_t)rw * N + cl] = __builtin_amdgcn_exp2f(v);
        }
}

// ---------------- mu partials: register-tiled 1j x 4i, 4-way rcp combining ----------
// sum_{u in 4} n_u/q_u = (nA*dB + nB*dA) / (dA*dB),  q_u = Ea*Eb+1, dA=q0q1, dB=q2q3,
// nA = n0*q1+n1*q0, nB = n2*q3+n3*q2.  One v_rcp per 4 terms (was 4) -> 144 cy/c-iter
// (was 192).  den overflow needs all four q >= 3e9 simultaneously, where the true
// contribution is ~0 and num*rcp(inf)=0 degrades gracefully.
__global__ __launch_bounds__(256) void mu5_kernel(const float* __restrict__ Ea,
                                                  const float* __restrict__ Eb,
                                                  const float* __restrict__ nu2,
                                                  float* __restrict__ mu0,
                                                  float* __restrict__ mu1) {
    __shared__ float As[64][132];
    __shared__ float Bs[16][132];
    const int t = threadIdx.x;
    const int bx = blockIdx.x;
    const int us = bx & 1;
    const int it = (bx >> 1) & 7;
    const int jt = (bx >> 4) & 3;
    const int b  = bx >> 6;
    const int i0 = it * 64, j0 = jt * 16, u0 = us * 256;
    const int il = t & 15, jr = t >> 4;

    const float* aeb = Ea + (size_t)(b * ENW + i0) * UN;
    const float* beb = Eb + (size_t)(b * DEW + j0) * UN;

    float s0 = 0.f, s1 = 0.f, s2 = 0.f, s3 = 0.f;
#pragma unroll
    for (int half = 0; half < 2; ++half) {
        const int uc = u0 + half * 128;
#pragma unroll
        for (int q = 0; q < 8; ++q) {
            int idx = q * 256 + t;
            int rowi = idx >> 5, c4 = idx & 31;
            *(float4*)&As[rowi][c4 * 4] = *(const float4*)(aeb + (size_t)rowi * UN + uc + c4 * 4);
        }
#pragma unroll
        for (int q = 0; q < 2; ++q) {
            int idx = q * 256 + t;
            int rowi = idx >> 5, c4 = idx & 31;
            *(float4*)&Bs[rowi][c4 * 4] = *(const float4*)(beb + (size_t)rowi * UN + uc + c4 * 4);
        }
        __syncthreads();
#pragma unroll 8
        for (int c = 0; c < 32; ++c) {
            float4 bb = *(const float4*)&Bs[jr][c * 4];
            float4 nv = *(const float4*)(nu2 + uc + c * 4);   // uniform -> s_load
            float4 a0 = *(const float4*)&As[il][c * 4];
            float4 a1 = *(const float4*)&As[il + 16][c * 4];
            float4 a2 = *(const float4*)&As[il + 32][c * 4];
            float4 a3 = *(const float4*)&As[il + 48][c * 4];
            {
                float q0 = fmaf(a0.x, bb.x, 1.f), q1 = fmaf(a0.y, bb.y, 1.f);
                float q2 = fmaf(a0.z, bb.z, 1.f), q3 = fmaf(a0.w, bb.w, 1.f);
                float dA = q0 * q1, dB = q2 * q3;
                float nA = fmaf(nv.y, q0, nv.x * q1);
                float nB = fmaf(nv.w, q2, nv.z * q3);
                float num = fmaf(nB, dA, nA * dB);
                s0 = fmaf(num, __builtin_amdgcn_rcpf(dA * dB), s0);
            }
            {
                float q0 = fmaf(a1.x, bb.x, 1.f), q1 = fmaf(a1.y, bb.y, 1.f);
                float q2 = fmaf(a1.z, bb.z, 1.f), q3 = fmaf(a1.w, bb.w, 1.f);
                float dA = q0 * q1, dB = q2 * q3;
                float nA = fmaf(nv.y, q0, nv.x * q1);
                float nB = fmaf(nv.w, q2, nv.z * q3);
                float num = fmaf(nB, dA, nA * dB);
                s1 = fmaf(num, __builtin_amdgcn_rcpf(dA * dB), s1);
            }
            {
                float q0 = fmaf(a2.x, bb.x, 1.f), q1 = fmaf(a2.y, bb.y, 1.f);
                float q2 = fmaf(a2.z, bb.z, 1.f), q3 = fmaf(a2.w, bb.w, 1.f);
                float dA = q0 * q1, dB = q2 * q3;
                float nA = fmaf(nv.y, q0, nv.x * q1);
                float nB = fmaf(nv.w, q2, nv.z * q3);
                float num = fmaf(nB, dA, nA * dB);
                s2 = fmaf(num, __builtin_amdgcn_rcpf(dA * dB), s2);
            }
            {
                float q0 = fmaf(a3.x, bb.x, 1.f), q1 = fmaf(a3.y, bb.y, 1.f);
                float q2 = fmaf(a3.z, bb.z, 1.f), q3 = fmaf(a3.w, bb.w, 1.f);
                float dA = q0 * q1, dB = q2 * q3;
                float nA = fmaf(nv.y, q0, nv.x * q1);
                float nB = fmaf(nv.w, q2, nv.z * q3);
                float num = fmaf(nB, dA, nA * dB);
                s3 = fmaf(num, __builtin_amdgcn_rcpf(dA * dB), s3);
            }
        }
        __syncthreads();
    }
    float* mo = us ? mu1 : mu0;
    const size_t base = (size_t)(b * DEW + j0 + jr) * ENW + i0 + il;
    mo[base]      = s0;
    mo[base + 16] = s1;
    mo[base + 32] = s2;
    mo[base + 48] = s3;
}

// ---------------- fused softmax + p_gen + alphas + out ----------------
// grid 256: eh=bx&1, jq=(bx>>1)&15, b=bx>>5. 4 waves: phase1 wave=j (softmax);
// phase2 wave=i-quarter, lane=4e of this e-half; phase3 LDS cross-wave reduce.
// mu = mu0 + mu1 + snu (u-split partials recombined here).
__global__ __launch_bounds__(256) void softfin_kernel(const float* __restrict__ mu0,
                                                      const float* __restrict__ mu1,
                                                      const float* __restrict__ snu,
                                                      const float* __restrict__ en,
                                                      const float* __restrict__ de,
                                                      float* __restrict__ out,
                                                      float* __restrict__ alphas,
                                                      float* __restrict__ p_gen) {
    __shared__ float Al[4][512];
    __shared__ float Ps[4][4][256];
    const int bx = blockIdx.x;
    const int eh = bx & 1;
    const int jq = (bx >> 1) & 15;
    const int b  = bx >> 5;
    const int t = threadIdx.x;
    const int wave = t >> 6, lane = t & 63;
    const int j0 = jq * 4;
    const float snu0 = snu[0];

    // ---- phase 1: softmax for j = j0 + wave ----
    {
        const int bj = b * DEW + j0 + wave;
        const float* mup0 = mu0 + (size_t)bj * ENW;
        const float* mup1 = mu1 + (size_t)bj * ENW;
        float v[8], a[8];
#pragma unroll
        for (int c = 0; c < 8; ++c) v[c] = mup0[c * 64 + lane] + mup1[c * 64 + lane] + snu0;
        float mx = v[0];
#pragma unroll
        for (int c = 1; c < 8; ++c) mx = fmaxf(mx, v[c]);
#pragma unroll
        for (int off = 32; off > 0; off >>= 1) mx = fmaxf(mx, __shfl_xor(mx, off));
        float s = 0.f;
#pragma unroll
        for (int c = 0; c < 8; ++c) { a[c] = __builtin_amdgcn_exp2f((v[c] - mx) * L2E); s += a[c]; }
#pragma unroll
        for (int off = 32; off > 0; off >>= 1) s += __shfl_xor(s, off);
        float inv = __builtin_amdgcn_rcpf(s);
#pragma unroll
        for (int c = 0; c < 8; ++c) {
            a[c] *= inv;
            Al[wave][c * 64 + lane] = a[c];
        }
        if (eh == 0) {
            float* alp = alphas + (size_t)bj * ENW;
            float* pgp = p_gen + (size_t)bj * ENW;
#pragma unroll
            for (int c = 0; c < 8; ++c) {
                alp[c * 64 + lane] = a[c];
                pgp[c * 64 + lane] = __builtin_amdgcn_rcpf(1.f + __builtin_amdgcn_exp2f(-v[c] * L2E));
            }
        }
    }
    __syncthreads();

    // ---- phase 2: partial sums over i-quarter `wave` ----
    const int i0 = wave * 128;
    const float* enb = en + (size_t)b * ENW * EMB + eh * 256 + lane * 4;
    f32x4 acc[4];
#pragma unroll
    for (int jj = 0; jj < 4; ++jj) acc[jj] = 0.f;
#pragma unroll 2
    for (int ig = 0; ig < 128; ig += 4) {
        const int ib = i0 + ig;
        float4 al0 = *(const float4*)&Al[0][ib];
        float4 al1 = *(const float4*)&Al[1][ib];
        float4 al2 = *(const float4*)&Al[2][ib];
        float4 al3 = *(const float4*)&Al[3][ib];
#pragma unroll
        for (int r = 0; r < 4; ++r) {
            float4 x = *(const float4*)(enb + (size_t)(ib + r) * EMB);
            float w0 = (r == 0) ? al0.x : (r == 1) ? al0.y : (r == 2) ? al0.z : al0.w;
            float w1 = (r == 0) ? al1.x : (r == 1) ? al1.y : (r == 2) ? al1.z : al1.w;
            float w2 = (r == 0) ? al2.x : (r == 1) ? al2.y : (r == 2) ? al2.z : al2.w;
            float w3 = (r == 0) ? al3.x : (r == 1) ? al3.y : (r == 2) ? al3.z : al3.w;
            acc[0][0] = fmaf(w0, x.x, acc[0][0]); acc[0][1] = fmaf(w0, x.y, acc[0][1]);
            acc[0][2] = fmaf(w0, x.z, acc[0][2]); acc[0][3] = fmaf(w0, x.w, acc[0][3]);
            acc[1][0] = fmaf(w1, x.x, acc[1][0]); acc[1][1] = fmaf(w1, x.y, acc[1][1]);
            acc[1][2] = fmaf(w1, x.z, acc[1][2]); acc[1][3] = fmaf(w1, x.w, acc[1][3]);
            acc[2][0] = fmaf(w2, x.x, acc[2][0]); acc[2][1] = fmaf(w2, x.y, acc[2][1]);
            acc[2][2] = fmaf(w2, x.z, acc[2][2]); acc[2][3] = fmaf(w2, x.w, acc[2][3]);
            acc[3][0] = fmaf(w3, x.x, acc[3][0]); acc[3][1] = fmaf(w3, x.y, acc[3][1]);
            acc[3][2] = fmaf(w3, x.z, acc[3][2]); acc[3][3] = fmaf(w3, x.w, acc[3][3]);
        }
    }
#pragma unroll
    for (int jj = 0; jj < 4; ++jj)
        *(f32x4*)&Ps[wave][jj][lane * 4] = acc[jj];
    __syncthreads();

    // ---- phase 3: reduce over i-quarters; wave handles its own j ----
    {
        const int bj = b * DEW + j0 + wave;
        const int e = eh * 256 + lane * 4;
        float4 p0 = *(const float4*)&Ps[0][wave][lane * 4];
        float4 p1 = *(const float4*)&Ps[1][wave][lane * 4];
        float4 p2 = *(const float4*)&Ps[2][wave][lane * 4];
        float4 p3 = *(const float4*)&Ps[3][wave][lane * 4];
        float4 d = *(const float4*)(de + (size_t)bj * EMB + e);
        float4 o;
        o.x = d.x + (p0.x + p1.x) + (p2.x + p3.x);
        o.y = d.y + (p0.y + p1.y) + (p2.y + p3.y);
        o.z = d.z + (p0.z + p1.z) + (p2.z + p3.z);
        o.w = d.w + (p0.w + p1.w) + (p2.w + p3.w);
        *(float4*)(out + (size_t)bj * EMB + e) = o;
    }
}

extern "C" void kernel_launch(void* const* d_in, const int* in_sizes, int n_in,
                              void* d_out, int out_size, void* d_ws, size_t ws_size,
                              hipStream_t stream) {
    const float* en     = (const float*)d_in[0];  // [8][512][512]
    const float* de     = (const float*)d_in[1];  // [8][64][512]
    const float* topics = (const float*)d_in[2];  // [8][100]
    const float* w_en   = (const float*)d_in[3];  // [512][512]
    const float* w_de   = (const float*)d_in[4];  // [512][512]
    const float* nu     = (const float*)d_in[5];  // [512]
    const float* wt     = (const float*)d_in[6];  // [512][100]

    float* out    = (float*)d_out;        // [8][64][512]
    float* alphas = out + 262144;
    float* p_gen  = out + 524288;

    // Workspace layout (total 15,222,800 B — below proven 16,271,376 B bound).
    // mu0/mu1 ALIAS the en_bf region: en_bf is dead after gemm_fused, mu0/mu1 are
    // first written by mu5_kernel (strictly later on the same stream).
    char* ws = (char*)d_ws;
    float* Ea             = (float*)(ws);                       //  8388608 B
    float* Eb             = (float*)(ws + 8388608);             //  1048576 B
    float* tw2            = (float*)(ws + 9437184);             //    16384 B
    unsigned short* en_bf = (unsigned short*)(ws + 9453568);    //  4194304 B
    float* mu0            = (float*)(ws + 9453568);             //  1048576 B (alias en_bf)
    float* mu1            = (float*)(ws + 10502144);            //  1048576 B (alias en_bf)
    unsigned short* de_bf = (unsigned short*)(ws + 13647872);   //   524288 B
    unsigned short* wen_t = (unsigned short*)(ws + 14172160);   //   524288 B
    unsigned short* wde_t = (unsigned short*)(ws + 14696448);   //   524288 B
    float* snu            = (float*)(ws + 15220736);            //       16 B
    float* nu2            = (float*)(ws + 15220752);            //     2048 B

    prep_kernel<<<1297, 256, 0, stream>>>(w_en, w_de, en, de, topics, wt, nu,
                                          wen_t, wde_t, en_bf, de_bf, tw2, snu, nu2);
    gemm_fused<<<dim3(72, 8), 256, 0, stream>>>(en_bf, de_bf, wen_t, wde_t, tw2, Ea, Eb);
    mu5_kernel<<<512, 256, 0, stream>>>(Ea, Eb, nu2, mu0, mu1);
    softfin_kernel<<<256, 256, 0, stream>>>(mu0, mu1, snu, en, de, out, alphas, p_gen);
}